// Round 1
// baseline (52.726 us; speedup 1.0000x reference)
//
#include <hip/hip_runtime.h>
#include <math.h>

#define BLK 256

// Brill-Lindquist Christoffel symbols.
// G = psi^4 * I  =>  G^{-1} = psi^{-4} * I,
// dG[b,i,l,k] = delta_il * D_k,  D_k = (psi^4(x+e_k*eps) - psi^4(x-e_k*eps)) / (2 eps)
// C^k_ij = delta_ik*q_j + delta_jk*q_i - delta_ij*q_k,  q_k = 0.5 * psi^{-4} * D_k
__global__ __launch_bounds__(BLK) void bl_christoffel_kernel(
    const float* __restrict__ x,        // [B,3]
    const float* __restrict__ masses,   // [2]
    const float* __restrict__ centers,  // [2,3]
    float* __restrict__ out,            // [B,3,3,3]
    int B)
{
    __shared__ float qs[BLK * 3];

    const int tid   = threadIdx.x;
    const int bbase = blockIdx.x * BLK;
    const int b     = bbase + tid;

    // Uniform (scalar) loads of masses/centers.
    const double m0  = (double)masses[0];
    const double m1  = (double)masses[1];
    const double c00 = (double)centers[0], c01 = (double)centers[1], c02 = (double)centers[2];
    const double c10 = (double)centers[3], c11 = (double)centers[4], c12 = (double)centers[5];

    if (b < B) {
        const double x0 = (double)x[3 * b + 0];
        const double x1 = (double)x[3 * b + 1];
        const double x2 = (double)x[3 * b + 2];

        // psi^4 at a point
        auto psi4 = [&](double p0, double p1, double p2) -> double {
            double d0 = p0 - c00, d1 = p1 - c01, d2 = p2 - c02;
            double r0 = sqrt(d0 * d0 + d1 * d1 + d2 * d2);
            d0 = p0 - c10; d1 = p1 - c11; d2 = p2 - c12;
            double r1 = sqrt(d0 * d0 + d1 * d1 + d2 * d2);
            double ps = 1.0 + 0.5 * m0 / r0 + 0.5 * m1 / r1;
            double p2s = ps * ps;
            return p2s * p2s;
        };

        const double eps  = 1e-4;                 // matches reference EPS
        const double ide  = 1.0 / (2.0 * eps);
        const double g    = psi4(x0, x1, x2);     // psi^4 at center
        const double half_ginv = 0.5 / g;         // 0.5 * psi^{-4}

        double q0, q1, q2;
        {
            double gp = psi4(x0 + eps, x1, x2);
            double gm = psi4(x0 - eps, x1, x2);
            q0 = half_ginv * (gp - gm) * ide;
        }
        {
            double gp = psi4(x0, x1 + eps, x2);
            double gm = psi4(x0, x1 - eps, x2);
            q1 = half_ginv * (gp - gm) * ide;
        }
        {
            double gp = psi4(x0, x1, x2 + eps);
            double gm = psi4(x0, x1, x2 - eps);
            q2 = half_ginv * (gp - gm) * ide;
        }

        qs[tid * 3 + 0] = (float)q0;
        qs[tid * 3 + 1] = (float)q1;
        qs[tid * 3 + 2] = (float)q2;
    }

    __syncthreads();

    // Coalesced write of this block's [npts, 27] output region.
    const int npts  = min(BLK, B - bbase);
    const int total = npts * 27;
    float* o = out + (size_t)bbase * 27;

    for (int s = tid; s < total; s += BLK) {
        int p = s / 27;            // point within block
        int c = s - p * 27;        // component 0..26
        int k = c / 9;
        int r = c - k * 9;
        int i = r / 3;
        int j = r - i * 3;
        float v = 0.0f;
        if (i == k) v += qs[p * 3 + j];
        if (j == k) v += qs[p * 3 + i];
        if (i == j) v -= qs[p * 3 + k];
        o[s] = v;
    }
}

extern "C" void kernel_launch(void* const* d_in, const int* in_sizes, int n_in,
                              void* d_out, int out_size, void* d_ws, size_t ws_size,
                              hipStream_t stream) {
    const float* x       = (const float*)d_in[0];
    const float* masses  = (const float*)d_in[1];
    const float* centers = (const float*)d_in[2];
    float* out           = (float*)d_out;

    const int B = in_sizes[0] / 3;
    const int grid = (B + BLK - 1) / BLK;

    bl_christoffel_kernel<<<grid, BLK, 0, stream>>>(x, masses, centers, out, B);
}

// Round 2
// 35.387 us; speedup vs baseline: 1.4900x; 1.4900x over previous
//
#include <hip/hip_runtime.h>
#include <math.h>

#define BLK 256

// Brill-Lindquist Christoffel symbols, analytic form.
// psi = 1 + sum_i m_i / (2 r_i),  G = psi^4 I,  G^{-1} = psi^-4 I.
// C^k_ij = delta_ik q_j + delta_jk q_i - delta_ij q_k,
// q_k = 0.5 * (d_k psi^4) / psi^4 = 2 * (d_k psi) / psi,
// d_k psi = -sum_i m_i (x_k - c_ik) / (2 r_i^3).
// (Analytic vs reference's eps=1e-4 central FD differs by ~eps^2/r^2 ~ 1e-5
//  relative even at the closest-approach points — far inside the 2.5 threshold.)
__global__ __launch_bounds__(BLK) void bl_christoffel_kernel(
    const float* __restrict__ x,        // [B,3]
    const float* __restrict__ masses,   // [2]
    const float* __restrict__ centers,  // [2,3]
    float* __restrict__ out,            // [B,3,3,3]
    int B)
{
    __shared__ float qs[BLK * 3];

    const int tid   = threadIdx.x;
    const int bbase = blockIdx.x * BLK;
    const int b     = bbase + tid;

    const float m0h = 0.5f * masses[0];
    const float m1h = 0.5f * masses[1];
    const float c00 = centers[0], c01 = centers[1], c02 = centers[2];
    const float c10 = centers[3], c11 = centers[4], c12 = centers[5];

    if (b < B) {
        const float x0 = x[3 * b + 0];
        const float x1 = x[3 * b + 1];
        const float x2 = x[3 * b + 2];

        const float d00 = x0 - c00, d01 = x1 - c01, d02 = x2 - c02;
        const float d10 = x0 - c10, d11 = x1 - c11, d12 = x2 - c12;

        const float ir0 = rsqrtf(d00 * d00 + d01 * d01 + d02 * d02);
        const float ir1 = rsqrtf(d10 * d10 + d11 * d11 + d12 * d12);

        const float psi = 1.0f + m0h * ir0 + m1h * ir1;
        const float a0  = m0h * ir0 * ir0 * ir0;   // m0/(2 r0^3)
        const float a1  = m1h * ir1 * ir1 * ir1;   // m1/(2 r1^3)
        const float s   = -2.0f / psi;             // q = 2 grad(psi)/psi

        qs[tid * 3 + 0] = s * (a0 * d00 + a1 * d10);
        qs[tid * 3 + 1] = s * (a0 * d01 + a1 * d11);
        qs[tid * 3 + 2] = s * (a0 * d02 + a1 * d12);
    }

    __syncthreads();

    const int npts = min(BLK, B - bbase);
    float* o = out + (size_t)bbase * 27;

    if (npts == BLK) {
        // Full block: vectorized float4 stores over the 6912-float region.
        float4* o4 = (float4*)o;
        const int total4 = BLK * 27 / 4;  // 1728
        for (int s4 = tid; s4 < total4; s4 += BLK) {
            const int base = s4 * 4;
            float vv[4];
#pragma unroll
            for (int e = 0; e < 4; ++e) {
                const int s = base + e;
                const int p = s / 27;
                const int c = s - p * 27;
                const int k = c / 9;
                const int r = c - k * 9;
                const int i = r / 3;
                const int j = r - i * 3;
                float v = 0.0f;
                if (i == k) v += qs[p * 3 + j];
                if (j == k) v += qs[p * 3 + i];
                if (i == j) v -= qs[p * 3 + k];
                vv[e] = v;
            }
            o4[s4] = make_float4(vv[0], vv[1], vv[2], vv[3]);
        }
    } else {
        // Tail block: scalar coalesced stores.
        const int total = npts * 27;
        for (int s = tid; s < total; s += BLK) {
            const int p = s / 27;
            const int c = s - p * 27;
            const int k = c / 9;
            const int r = c - k * 9;
            const int i = r / 3;
            const int j = r - i * 3;
            float v = 0.0f;
            if (i == k) v += qs[p * 3 + j];
            if (j == k) v += qs[p * 3 + i];
            if (i == j) v -= qs[p * 3 + k];
            o[s] = v;
        }
    }
}

extern "C" void kernel_launch(void* const* d_in, const int* in_sizes, int n_in,
                              void* d_out, int out_size, void* d_ws, size_t ws_size,
                              hipStream_t stream) {
    const float* x       = (const float*)d_in[0];
    const float* masses  = (const float*)d_in[1];
    const float* centers = (const float*)d_in[2];
    float* out           = (float*)d_out;

    const int B = in_sizes[0] / 3;
    const int grid = (B + BLK - 1) / BLK;

    bl_christoffel_kernel<<<grid, BLK, 0, stream>>>(x, masses, centers, out, B);
}

// Round 3
// 24.594 us; speedup vs baseline: 2.1438x; 1.4388x over previous
//
#include <hip/hip_runtime.h>
#include <math.h>

#define BLK 256

// Brill-Lindquist Christoffel symbols, analytic form.
// psi = 1 + sum_i m_i/(2 r_i),  G = psi^4 I  =>  G^{-1} = psi^-4 I.
// C^k_ij = delta_ik q_j + delta_jk q_i - delta_ij q_k,  q_k = 2 (d_k psi)/psi.
// Every output element is exactly +q_m, -q_m, or 0:
//   i==j==k -> +q_k ; i==k!=j -> +q_j ; j==k!=i -> +q_i ; i==j!=k -> -q_k ; else 0.
// So phase 1 materializes each point's 27-value row straight into LDS
// (compile-time pattern, ds_write_b32 at 27-dword lane stride: gcd(27,32)=1
//  -> 2-way bank aliasing, free), and phase 2 is an identity LDS->global copy
// with ds_read_b128 + dwordx4 stores (no index math at all).
__global__ __launch_bounds__(BLK) void bl_christoffel_kernel(
    const float* __restrict__ x,        // [B,3]
    const float* __restrict__ masses,   // [2]
    const float* __restrict__ centers,  // [2,3]
    float* __restrict__ out,            // [B,3,3,3]
    int B)
{
    __shared__ float tile[BLK * 27];    // 27648 B: block's output image

    const int tid   = threadIdx.x;
    const int bbase = blockIdx.x * BLK;
    const int b     = bbase + tid;

    const float m0h = 0.5f * masses[0];
    const float m1h = 0.5f * masses[1];
    const float c00 = centers[0], c01 = centers[1], c02 = centers[2];
    const float c10 = centers[3], c11 = centers[4], c12 = centers[5];

    if (b < B) {
        const float x0 = x[3 * b + 0];
        const float x1 = x[3 * b + 1];
        const float x2 = x[3 * b + 2];

        const float d00 = x0 - c00, d01 = x1 - c01, d02 = x2 - c02;
        const float d10 = x0 - c10, d11 = x1 - c11, d12 = x2 - c12;

        const float ir0 = rsqrtf(d00 * d00 + d01 * d01 + d02 * d02);
        const float ir1 = rsqrtf(d10 * d10 + d11 * d11 + d12 * d12);

        const float psi = 1.0f + m0h * ir0 + m1h * ir1;
        const float a0  = m0h * ir0 * ir0 * ir0;   // m0/(2 r0^3)
        const float a1  = m1h * ir1 * ir1 * ir1;   // m1/(2 r1^3)
        const float s   = -2.0f / psi;             // q = 2 grad(psi)/psi

        const float q0 = s * (a0 * d00 + a1 * d10);
        const float q1 = s * (a0 * d01 + a1 * d11);
        const float q2 = s * (a0 * d02 + a1 * d12);
        const float n0 = -q0, n1 = -q1, n2 = -q2;

        float* lp = &tile[tid * 27];
        // c = k*9 + i*3 + j
        lp[ 0] = q0; lp[ 1] = q1; lp[ 2] = q2;   // k=0, i=0
        lp[ 3] = q1; lp[ 4] = n0; lp[ 5] = 0.f;  //      i=1
        lp[ 6] = q2; lp[ 7] = 0.f; lp[ 8] = n0;  //      i=2
        lp[ 9] = n1; lp[10] = q0; lp[11] = 0.f;  // k=1, i=0
        lp[12] = q0; lp[13] = q1; lp[14] = q2;   //      i=1
        lp[15] = 0.f; lp[16] = q2; lp[17] = n1;  //      i=2
        lp[18] = n2; lp[19] = 0.f; lp[20] = q0;  // k=2, i=0
        lp[21] = 0.f; lp[22] = n2; lp[23] = q1;  //      i=1
        lp[24] = q0; lp[25] = q1; lp[26] = q2;   //      i=2
    }

    __syncthreads();

    const int npts = min(BLK, B - bbase);
    float* o = out + (size_t)bbase * 27;

    if (npts == BLK) {
        // Identity copy: 6912 floats = 1728 float4 = 6.75 per thread.
        const float4* lsrc = (const float4*)tile;
        float4* o4 = (float4*)o;
#pragma unroll
        for (int n = 0; n < 6; ++n) {
            const int s4 = n * BLK + tid;
            o4[s4] = lsrc[s4];
        }
        const int s4 = 6 * BLK + tid;
        if (s4 < BLK * 27 / 4) o4[s4] = lsrc[s4];
    } else {
        const int total = npts * 27;
        for (int s = tid; s < total; s += BLK) o[s] = tile[s];
    }
}

extern "C" void kernel_launch(void* const* d_in, const int* in_sizes, int n_in,
                              void* d_out, int out_size, void* d_ws, size_t ws_size,
                              hipStream_t stream) {
    const float* x       = (const float*)d_in[0];
    const float* masses  = (const float*)d_in[1];
    const float* centers = (const float*)d_in[2];
    float* out           = (float*)d_out;

    const int B = in_sizes[0] / 3;
    const int grid = (B + BLK - 1) / BLK;

    bl_christoffel_kernel<<<grid, BLK, 0, stream>>>(x, masses, centers, out, B);
}